// Round 1
// baseline (124.605 us; speedup 1.0000x reference)
//
#include <hip/hip_runtime.h>
#include <cstddef>

#define B_SZ 32768
#define H_SZ 1024
#define N_SZ 4
#define C_SZ 1000
#define ROW_BLOCKS 256
#define ROWS_PER_BLOCK 128   // B_SZ / ROW_BLOCKS

// ---- workspace layout (in floats) ----
#define PART_SUM   0                      // 256*1024
#define PART_SQ    (PART_SUM + ROW_BLOCKS*H_SZ)   // 256*1024
#define WSUM_PART  (PART_SQ  + ROW_BLOCKS*H_SZ)   // 256
#define A_OFF      (WSUM_PART + 256)      // 1024  (gamma * inv_std)
#define C_OFF      (A_OFF + H_SZ)         // 1024  (beta - mean * a)
#define SCAL_OFF   (C_OFF + H_SZ)         // 1 (inv_wsum)  (+7 pad)
#define PCN_OFF    (SCAL_OFF + 8)         // 4000 (p_cn, zeroed per launch)

// ---- output layout (floats) ----
#define OUT_IG  ((size_t)B_SZ * H_SZ)          // 33554432
#define OUT_R   (OUT_IG + 1)                   // 33554433

// Pass 1: weighted column sums (skip masked-out rows -> ~half the reads)
__global__ void __launch_bounds__(256) k_colsum(const float* __restrict__ h,
                                                const int* __restrict__ mask,
                                                float* __restrict__ ws) {
    const int rb   = blockIdx.x;
    const int t    = threadIdx.x;          // 0..255
    const int row0 = rb * ROWS_PER_BLOCK;
    const int col  = t * 4;

    float4 s = make_float4(0.f, 0.f, 0.f, 0.f);
    float4 q = make_float4(0.f, 0.f, 0.f, 0.f);
    int mcount = 0;

    const float* p = h + (size_t)row0 * H_SZ + col;
    for (int r = 0; r < ROWS_PER_BLOCK; ++r) {
        const int m = mask[row0 + r];
        if (m) {
            float4 x = *(const float4*)p;
            s.x += x.x; s.y += x.y; s.z += x.z; s.w += x.w;
            q.x += x.x * x.x; q.y += x.y * x.y; q.z += x.z * x.z; q.w += x.w * x.w;
            ++mcount;
        }
        p += H_SZ;
    }
    *(float4*)(ws + PART_SUM + (size_t)rb * H_SZ + col) = s;
    *(float4*)(ws + PART_SQ  + (size_t)rb * H_SZ + col) = q;
    if (t == 0) ws[WSUM_PART + rb] = (float)mcount;
}

// Pass 2: finalize mean/var -> a[h], c[h], inv_wsum
__global__ void __launch_bounds__(256) k_colfinal(const float* __restrict__ gamma,
                                                  const float* __restrict__ beta,
                                                  float* __restrict__ ws) {
    __shared__ float red[256];
    const int t = threadIdx.x;

    // every block redundantly reduces the 256 wsum partials
    red[t] = ws[WSUM_PART + t];
    __syncthreads();
    for (int sft = 128; sft > 0; sft >>= 1) {
        if (t < sft) red[t] += red[t + sft];
        __syncthreads();
    }
    const float wsum = red[0];

    const int h = blockIdx.x * 256 + t;
    float s = 0.f, q = 0.f;
    for (int rb = 0; rb < ROW_BLOCKS; ++rb) {
        s += ws[PART_SUM + (size_t)rb * H_SZ + h];
        q += ws[PART_SQ  + (size_t)rb * H_SZ + h];
    }
    const float inv_w = 1.0f / wsum;
    const float mean  = s * inv_w;
    float var = q * inv_w - mean * mean;
    if (var < 0.f) var = 0.f;
    const float istd = rsqrtf(var + 1e-5f);
    const float a = gamma[h] * istd;
    const float c = beta[h] - mean * a;
    ws[A_OFF + h] = a;
    ws[C_OFF + h] = c;
    if (h == 0) ws[SCAL_OFF] = inv_w;
}

// Pass 3: fused normalize + (BxH)@(Hx4) + softmax + argmax routing + p_cn atomics
// one wave (64 lanes) per row; block = 4 waves
__global__ void __launch_bounds__(256) k_fused(const float* __restrict__ hin,
                                               const int* __restrict__ mask,
                                               const int* __restrict__ labels,
                                               const float* __restrict__ W,
                                               const float* __restrict__ bias,
                                               const float* __restrict__ ws,
                                               float* __restrict__ out,
                                               float* __restrict__ pcn) {
    const int wid  = threadIdx.x >> 6;
    const int lane = threadIdx.x & 63;
    const int row  = blockIdx.x * 4 + wid;

    const float* xr   = hin + (size_t)row * H_SZ;
    float*       outr = out + (size_t)row * H_SZ;

    float acc0 = 0.f, acc1 = 0.f, acc2 = 0.f, acc3 = 0.f;

#pragma unroll
    for (int ch = 0; ch < 4; ++ch) {
        const int h = ch * 256 + lane * 4;
        const float4 x = *(const float4*)(xr + h);
        const float4 a = *(const float4*)(ws + A_OFF + h);
        const float4 c = *(const float4*)(ws + C_OFF + h);
        float4 hn;
        hn.x = fmaf(x.x, a.x, c.x);
        hn.y = fmaf(x.y, a.y, c.y);
        hn.z = fmaf(x.z, a.z, c.z);
        hn.w = fmaf(x.w, a.w, c.w);
        *(float4*)(outr + h) = hn;

        const float4 w0 = *(const float4*)(W + (size_t)(h + 0) * 4);
        const float4 w1 = *(const float4*)(W + (size_t)(h + 1) * 4);
        const float4 w2 = *(const float4*)(W + (size_t)(h + 2) * 4);
        const float4 w3 = *(const float4*)(W + (size_t)(h + 3) * 4);
        acc0 = fmaf(hn.x, w0.x, acc0); acc1 = fmaf(hn.x, w0.y, acc1);
        acc2 = fmaf(hn.x, w0.z, acc2); acc3 = fmaf(hn.x, w0.w, acc3);
        acc0 = fmaf(hn.y, w1.x, acc0); acc1 = fmaf(hn.y, w1.y, acc1);
        acc2 = fmaf(hn.y, w1.z, acc2); acc3 = fmaf(hn.y, w1.w, acc3);
        acc0 = fmaf(hn.z, w2.x, acc0); acc1 = fmaf(hn.z, w2.y, acc1);
        acc2 = fmaf(hn.z, w2.z, acc2); acc3 = fmaf(hn.z, w2.w, acc3);
        acc0 = fmaf(hn.w, w3.x, acc0); acc1 = fmaf(hn.w, w3.y, acc1);
        acc2 = fmaf(hn.w, w3.z, acc2); acc3 = fmaf(hn.w, w3.w, acc3);
    }

    // wave reduce-all (64 lanes)
#pragma unroll
    for (int off = 1; off < 64; off <<= 1) {
        acc0 += __shfl_xor(acc0, off);
        acc1 += __shfl_xor(acc1, off);
        acc2 += __shfl_xor(acc2, off);
        acc3 += __shfl_xor(acc3, off);
    }
    acc0 += bias[0]; acc1 += bias[1]; acc2 += bias[2]; acc3 += bias[3];

    // first-occurrence argmax (matches jnp.argmax)
    int amax = 0; float best = acc0;
    if (acc1 > best) { best = acc1; amax = 1; }
    if (acc2 > best) { best = acc2; amax = 2; }
    if (acc3 > best) { best = acc3; amax = 3; }

    // softmax (TEMPERATURE = 1)
    const float e0 = expf(acc0 - best);
    const float e1 = expf(acc1 - best);
    const float e2 = expf(acc2 - best);
    const float e3 = expf(acc3 - best);
    const float inv = 1.0f / (e0 + e1 + e2 + e3);

    const int m = mask[row];
    if (lane < 4) {
        const float rv = (m && lane == amax) ? 1.0f : 0.0f;
        out[OUT_R + (size_t)row * 4 + lane] = rv;
        if (m) {
            const float pv = (lane == 0 ? e0 : lane == 1 ? e1 : lane == 2 ? e2 : e3)
                             * inv * ws[SCAL_OFF];
            atomicAdd(&pcn[labels[row] * 4 + lane], pv);
        }
    }
}

// Pass 4: info-gain finalize over p_cn (1000 x 4) -> scalar
__global__ void __launch_bounds__(256) k_ig(const float* __restrict__ pcn,
                                            float* __restrict__ out) {
    __shared__ float red[256];
    __shared__ float pn_sh[4];
    const int t = threadIdx.x;

    float pn[4] = {0.f, 0.f, 0.f, 0.f};
    for (int c = t; c < C_SZ; c += 256) {
        pn[0] += pcn[c * 4 + 0];
        pn[1] += pcn[c * 4 + 1];
        pn[2] += pcn[c * 4 + 2];
        pn[3] += pcn[c * 4 + 3];
    }
#pragma unroll
    for (int n = 0; n < 4; ++n) {
        red[t] = pn[n];
        __syncthreads();
        for (int sft = 128; sft > 0; sft >>= 1) {
            if (t < sft) red[t] += red[t + sft];
            __syncthreads();
        }
        if (t == 0) pn_sh[n] = red[0];
        __syncthreads();
    }

    const float l0 = 2.0f * logf(pn_sh[0] + 1e-30f);
    const float l1 = 2.0f * logf(pn_sh[1] + 1e-30f);
    const float l2 = 2.0f * logf(pn_sh[2] + 1e-30f);
    const float l3 = 2.0f * logf(pn_sh[3] + 1e-30f);

    float kv = 0.f;
    for (int c = t; c < C_SZ; c += 256) {
        const float v0 = pcn[c * 4 + 0];
        const float v1 = pcn[c * 4 + 1];
        const float v2 = pcn[c * 4 + 2];
        const float v3 = pcn[c * 4 + 3];
        const float pc  = v0 + v1 + v2 + v3;
        const float lpc = logf(pc + 1e-30f);
        kv += v0 * (logf(v0 + 1e-30f) - lpc - l0);
        kv += v1 * (logf(v1 + 1e-30f) - lpc - l1);
        kv += v2 * (logf(v2 + 1e-30f) - lpc - l2);
        kv += v3 * (logf(v3 + 1e-30f) - lpc - l3);
    }
    red[t] = kv;
    __syncthreads();
    for (int sft = 128; sft > 0; sft >>= 1) {
        if (t < sft) red[t] += red[t + sft];
        __syncthreads();
    }
    if (t == 0) out[OUT_IG] = -red[0];
}

extern "C" void kernel_launch(void* const* d_in, const int* in_sizes, int n_in,
                              void* d_out, int out_size, void* d_ws, size_t ws_size,
                              hipStream_t stream) {
    const int*   ig_mask = (const int*)d_in[0];
    const float* h_net   = (const float*)d_in[1];
    const int*   labels  = (const int*)d_in[2];
    const float* gamma   = (const float*)d_in[3];
    const float* beta    = (const float*)d_in[4];
    const float* W       = (const float*)d_in[5];
    const float* b       = (const float*)d_in[6];

    float* out = (float*)d_out;
    float* ws  = (float*)d_ws;

    // p_cn must start at zero every launch (harness does not re-poison ws)
    hipMemsetAsync(ws + PCN_OFF, 0, C_SZ * N_SZ * sizeof(float), stream);

    k_colsum<<<ROW_BLOCKS, 256, 0, stream>>>(h_net, ig_mask, ws);
    k_colfinal<<<H_SZ / 256, 256, 0, stream>>>(gamma, beta, ws);
    k_fused<<<B_SZ / 4, 256, 0, stream>>>(h_net, ig_mask, labels, W, b, ws, out,
                                          ws + PCN_OFF);
    k_ig<<<1, 256, 0, stream>>>(ws + PCN_OFF, out);
}